// Round 7
// baseline (2754.936 us; speedup 1.0000x reference)
//
#include <hip/hip_runtime.h>
#include <hip/hip_bf16.h>

typedef __bf16 bf16;
typedef __bf16 bf16x8 __attribute__((ext_vector_type(8)));
typedef __bf16 bf16x4v __attribute__((ext_vector_type(4)));
typedef float f32x4 __attribute__((ext_vector_type(4)));

#define MODE_BIAS 1
#define MODE_RELU 2
#define MODE_BF16 4
#define MODE_F32  8
#define MODE_RES  16    // f32 residual
#define MODE_RESB 32    // bf16 residual
#define MODE_QKV  128
#define MODE_PART 256   // split-K: write f32 partial at Cf + z*qstride

// ---------------------------------------------------------------------------
// Async 16B global->LDS stage
// ---------------------------------------------------------------------------
__device__ __forceinline__ void stage16(const bf16* g, bf16* l)
{
  __builtin_amdgcn_global_load_lds(
      (const __attribute__((address_space(1))) void*)g,
      (__attribute__((address_space(3))) void*)l, 16, 0, 0);
}

// ---------------------------------------------------------------------------
// gemm2: C[M,N] = A[M,K]*B^T (B is [N,K]).  M%128==0, N%128==0, K%32==0.
// 128x128 tile.  K-loop = 3-slab ring at BK=32 with ONE barrier per step:
//   phase t: ds_read slab t -> issue stage slab t+2 -> vmcnt(4) [slab t+1
//   landed, own] -> MFMA -> lgkmcnt(0) -> s_barrier.
// The single trailing barrier guarantees BOTH (a) all waves' slab-t reads
// retired (slot (t+3)%3 safe to stage next phase) and (b) all waves' slab
// t+1 loads landed (each waited own vmcnt(4) pre-barrier) -> next phase
// reads immediately.  r4/r6 diagnosis: per-step wall ~1100-1300 cyc was
// invariant to occupancy (3 vs 5 blk/CU) and prefetch depth -> the fixed
// cost was the TWO per-step barrier rendezvous; this halves it without
// touching tile/VGPR (r3 lesson: don't trade occupancy for density).
// 48 KB LDS -> 3 blocks/CU.  16B k-units XOR-swizzled via inverse-permuted
// GLOBAL source + permuted ds_read offset (conflict-free, verified r2/r4).
// r5 lesson: no cross-XCD atomics; MODE_PART writes per-z partial buffers.
// ---------------------------------------------------------------------------
__global__ __launch_bounds__(256) void gemm2(
    const bf16* __restrict__ A, const bf16* __restrict__ B,
    float* __restrict__ Cf, bf16* __restrict__ Cb,
    const float* __restrict__ bias, const float* __restrict__ resf,
    const bf16* __restrict__ resb,
    int N, int K, int lda, int ldb, int ldc, long qstride, int mode)
{
  __shared__ __attribute__((aligned(16))) bf16 smem[24576];  // 48 KB
  bf16* sA = smem;             // [3 slabs][128][32]
  bf16* sB = smem + 12288;     // [3 slabs][128][32]

  int tid  = threadIdx.x;
  int lane = tid & 63;
  int wave = tid >> 6;
  int wm = (wave >> 1) * 64;
  int wn = (wave & 1) * 64;

  // XCD-chunked bijective swizzle (m204 variant), per z-slice
  int nwg = gridDim.x * gridDim.y;
  int i0  = blockIdx.y * gridDim.x + blockIdx.x;
  int q   = nwg >> 3, r = nwg & 7;
  int xcd = i0 & 7, jj = i0 >> 3;
  int lid = (xcd < r ? xcd * (q + 1) : r * (q + 1) + (xcd - r) * q) + jj;
  int bx = lid % gridDim.x;
  int by = lid / gridDim.x;
  int bm0 = bx * 128;
  int bn0 = by * 128;
  long ks = (long)blockIdx.z * K;      // K-split column offset

  f32x4 acc[4][4];
  #pragma unroll
  for (int i = 0; i < 4; ++i)
    #pragma unroll
    for (int j = 0; j < 4; ++j)
      #pragma unroll
      for (int rr = 0; rr < 4; ++rr) acc[i][j][rr] = 0.f;

  int seg0 = wave, seg1 = wave + 4;
  int csw = ((lane & 3) ^ ((lane >> 3) & 3)) * 16;   // swizzled byte col
  int r0s = seg0 * 16 + (lane >> 2);
  int r1s = seg1 * 16 + (lane >> 2);
  int rx = ((lane >> 4) ^ ((lane >> 1) & 3)) * 8;    // swizzled read offset

  const char* gA0 = (const char*)A + ((long)(bm0 + r0s) * lda + ks) * 2 + csw;
  const char* gA1 = (const char*)A + ((long)(bm0 + r1s) * lda + ks) * 2 + csw;
  const char* gB0 = (const char*)B + ((long)(bn0 + r0s) * ldb + ks) * 2 + csw;
  const char* gB1 = (const char*)B + ((long)(bn0 + r1s) * ldb + ks) * 2 + csw;

  int nt = K >> 5;                         // BK=32 steps (nt >= 2)

  // prologue: stage slabs 0,1 (4 VMEM each, per wave)
  stage16((const bf16*)gA0, sA + seg0 * 512);
  stage16((const bf16*)gA1, sA + seg1 * 512);
  stage16((const bf16*)gB0, sB + seg0 * 512);
  stage16((const bf16*)gB1, sB + seg1 * 512);
  stage16((const bf16*)(gA0 + 64), sA + 4096 + seg0 * 512);
  stage16((const bf16*)(gA1 + 64), sA + 4096 + seg1 * 512);
  stage16((const bf16*)(gB0 + 64), sB + 4096 + seg0 * 512);
  stage16((const bf16*)(gB1 + 64), sB + 4096 + seg1 * 512);
  asm volatile("s_waitcnt vmcnt(4)" ::: "memory");     // slab 0 landed (own)
  asm volatile("s_barrier" ::: "memory");              // everyone's slab 0 in

  int slot = 0, sslot = 2;
  for (int t = 0; t < nt; ++t) {
    int po = slot * 4096;
    bf16x8 aF[4], bF[4];
    #pragma unroll
    for (int i = 0; i < 4; ++i)
      aF[i] = *(const bf16x8*)(&sA[po + (wm + i * 16 + (lane & 15)) * 32 + rx]);
    #pragma unroll
    for (int j = 0; j < 4; ++j)
      bF[j] = *(const bf16x8*)(&sB[po + (wn + j * 16 + (lane & 15)) * 32 + rx]);
    if (t + 2 < nt) {
      long ob = (long)(t + 2) * 64;
      int so = sslot * 4096;
      stage16((const bf16*)(gA0 + ob), sA + so + seg0 * 512);
      stage16((const bf16*)(gA1 + ob), sA + so + seg1 * 512);
      stage16((const bf16*)(gB0 + ob), sB + so + seg0 * 512);
      stage16((const bf16*)(gB1 + ob), sB + so + seg1 * 512);
      asm volatile("s_waitcnt vmcnt(4)" ::: "memory"); // slab t+1 landed (own)
    } else {
      asm volatile("s_waitcnt vmcnt(0)" ::: "memory");
    }
    __builtin_amdgcn_s_setprio(1);
    #pragma unroll
    for (int i = 0; i < 4; ++i)
      #pragma unroll
      for (int j = 0; j < 4; ++j)
        acc[i][j] = __builtin_amdgcn_mfma_f32_16x16x32_bf16(aF[i], bF[j], acc[i][j], 0, 0, 0);
    __builtin_amdgcn_s_setprio(0);
    asm volatile("s_waitcnt lgkmcnt(0)" ::: "memory"); // my slab-t reads done
    asm volatile("s_barrier" ::: "memory");            // reads done + t+1 in
    slot = (slot == 2) ? 0 : slot + 1;
    sslot = (sslot == 2) ? 0 : sslot + 1;
  }

  int lg = lane >> 4;
  int r0 = lg * 4;
  int cc = lane & 15;

  if (mode & MODE_PART) {
    // ---- split-K: streamed f32 partial store (own buffer per z-slice) ----
    float* Cfz = Cf + (long)blockIdx.z * qstride;
    #pragma unroll
    for (int j = 0; j < 4; ++j) {
      int gn = bn0 + wn + j * 16 + cc;
      #pragma unroll
      for (int i = 0; i < 4; ++i)
        #pragma unroll
        for (int rr = 0; rr < 4; ++rr) {
          int gm = bm0 + wm + i * 16 + r0 + rr;
          Cfz[(long)gm * ldc + gn] = acc[i][j][rr];
        }
    }
    return;
  }

  if ((mode & MODE_QKV) && bn0 >= 8192) {
    // ---- V: transposed coalesced store via LDS (smem reused; K-loop done) ----
    bf16* sS = smem;   // [64][130] = 16.6 KB
    int nn0 = bn0 - 8192;
    #pragma unroll
    for (int ph = 0; ph < 2; ++ph) {
      if ((wn >> 6) == ph) {
        #pragma unroll
        for (int j = 0; j < 4; ++j) {
          int nl = j * 16 + cc;
          float bv = bias[bn0 + wn + j * 16 + cc];
          #pragma unroll
          for (int i = 0; i < 4; ++i)
            #pragma unroll
            for (int rr = 0; rr < 4; ++rr) {
              int m = wm + i * 16 + r0 + rr;
              sS[nl * 130 + m] = (bf16)(acc[i][j][rr] + bv);
            }
        }
      }
      __syncthreads();
      #pragma unroll
      for (int u = 0; u < 16; ++u) {
        int nrow = u * 4 + wave;
        int d = nn0 + ph * 64 + nrow;
        int hh = d >> 9, dd = d & 511;
        unsigned int pv = *(const unsigned int*)&sS[nrow * 130 + lane * 2];
        int m0 = bm0 + 2 * lane;
        int bl = m0 / 168;
        int s  = m0 - bl * 168;
        *(unsigned int*)&Cb[2 * qstride + ((long)(bl * 8 + hh) * 512 + dd) * 168 + s] = pv;
      }
      __syncthreads();
    }
    return;
  }

  if (mode & (MODE_QKV | MODE_BF16)) {
    // ---- bf16 coalesced store, two 64-row phases ([64][136] = 17.4 KB) ----
    bf16* sS = smem;
    long base;
    int ldx;
    if (mode & MODE_QKV) {
      int part = bn0 >> 12;           // 0=Q 1=K; tile never straddles parts
      base = (long)part * qstride + (bn0 & 4095);
      ldx = 4096;
    } else {
      base = (long)bn0;
      ldx = ldc;
    }
    #pragma unroll
    for (int ph = 0; ph < 2; ++ph) {
      if ((wm >> 6) == ph) {
        #pragma unroll
        for (int j = 0; j < 4; ++j) {
          float bv = (mode & MODE_BIAS) ? bias[bn0 + wn + j * 16 + cc] : 0.f;
          #pragma unroll
          for (int i = 0; i < 4; ++i) {
            #pragma unroll
            for (int rr = 0; rr < 4; ++rr) {
              float v = acc[i][j][rr] + bv;
              if (mode & MODE_RELU) v = fmaxf(v, 0.f);
              sS[(i * 16 + r0 + rr) * 136 + wn + j * 16 + cc] = (bf16)v;
            }
          }
        }
      }
      __syncthreads();
      #pragma unroll
      for (int it = 0; it < 4; ++it) {
        int idx = it * 256 + tid;
        int row = idx >> 4, seg = idx & 15;
        bf16x8 v = *(const bf16x8*)&sS[row * 136 + seg * 8];
        *(bf16x8*)&Cb[base + (long)(bm0 + ph * 64 + row) * ldx + seg * 8] = v;
      }
      __syncthreads();
    }
    return;
  }

  // ---- generic f32/bf16 epilogue (mo uses RESB path) ----
  #pragma unroll
  for (int j = 0; j < 4; ++j) {
    int gn = bn0 + wn + j * 16 + cc;
    float bv = (mode & MODE_BIAS) ? bias[gn] : 0.f;
    #pragma unroll
    for (int i = 0; i < 4; ++i) {
      #pragma unroll
      for (int rr = 0; rr < 4; ++rr) {
        int gm = bm0 + wm + i * 16 + r0 + rr;
        float v = acc[i][j][rr] + bv;
        if (mode & MODE_RES)  v += resf[(long)gm * ldc + gn];
        if (mode & MODE_RESB) v += (float)resb[(long)gm * ldc + gn];
        if (mode & MODE_RELU) v = fmaxf(v, 0.f);
        if (mode & MODE_F32) {
          Cf[(long)gm * ldc + gn] = v;
        } else {
          Cb[(long)gm * ldc + gn] = (bf16)v;
        }
      }
    }
  }
}

// ---------------------------------------------------------------------------
// dn_reduce: Xf[i] = P0[i]+P1[i]+P2[i]+P3[i] + hF[i] + bias[i&511]
// ---------------------------------------------------------------------------
__global__ __launch_bounds__(256) void dn_reduce(
    float* __restrict__ Xf, const float* __restrict__ P,
    const float* __restrict__ hF, const float* __restrict__ bias,
    long n, long pstride)
{
  long i = ((long)blockIdx.x * 256 + threadIdx.x) * 4;
  if (i >= n) return;
  int d = (int)(i & 511);
  float4 v  = *(const float4*)&hF[i];
  float4 bv = *(const float4*)&bias[d];
  v.x += bv.x; v.y += bv.y; v.z += bv.z; v.w += bv.w;
  #pragma unroll
  for (int z = 0; z < 4; ++z) {
    float4 p = *(const float4*)&P[(long)z * pstride + i];
    v.x += p.x; v.y += p.y; v.z += p.z; v.w += p.w;
  }
  *(float4*)&Xf[i] = v;
}

// ---------------------------------------------------------------------------
// FUSED ATTENTION (r2-proven): per (m-tile of 64 q-rows, bh) block.
// QK^T loop: 2-slab double buffer with COUNTED vmcnt(4) + raw barriers.
// ---------------------------------------------------------------------------
__global__ __launch_bounds__(256) void attn_fused(
    const bf16* __restrict__ Q, const bf16* __restrict__ K,
    const bf16* __restrict__ Vt, bf16* __restrict__ O)
{
  __shared__ __attribute__((aligned(16))) bf16 sQ[2 * 64 * 32];
  __shared__ __attribute__((aligned(16))) bf16 sK[2 * 192 * 32];
  __shared__ __attribute__((aligned(16))) bf16 sP[64 * 200];
  __shared__ __attribute__((aligned(16))) bf16 sV[256 * 32];

  int mt = blockIdx.x;
  int bh = blockIdx.y;
  int bl = bh >> 3, h = bh & 7;
  int tid = threadIdx.x, lane = tid & 63, wave = tid >> 6;

  const bf16* Qb = Q + ((long)bl * 168 + mt * 64) * 4096 + h * 512;
  const bf16* Kb = K + (long)bl * 168 * 4096 + h * 512;
  const bf16* Vb = Vt + (long)bh * 512 * 168;

  #pragma unroll
  for (int idx = tid; idx < 64 * 16; idx += 256) {
    int rr = idx >> 4;
    sP[rr * 200 + 176 + (idx & 15)] = (bf16)0.f;
  }

  int srw = wave * 16 + (lane >> 2);
  int scb = ((lane & 3) ^ ((lane >> 3) & 3)) * 16;
  int rx  = ((lane >> 4) ^ ((lane >> 1) & 3)) * 8;

  const char* gQ = (const char*)Qb + (long)srw * 8192 + scb;
  const char* gK = (const char*)Kb + (long)srw * 8192 + scb;

  f32x4 sacc[11];
  #pragma unroll
  for (int j = 0; j < 11; ++j)
    #pragma unroll
    for (int rr = 0; rr < 4; ++rr) sacc[j][rr] = 0.f;

  stage16((const bf16*)gQ, &sQ[wave * 512]);
  stage16((const bf16*)gK, &sK[wave * 512]);
  stage16((const bf16*)(gK + 64 * 8192), &sK[(wave + 4) * 512]);
  stage16((const bf16*)(gK + 128 * 8192), &sK[(wave + 8) * 512]);

  for (int t = 0; t < 16; ++t) {
    int p = t & 1;
    if (t < 15) {
      long ob = (long)(t + 1) * 64;
      int bq = (p ^ 1) * 2048, bk = (p ^ 1) * 6144;
      stage16((const bf16*)(gQ + ob), &sQ[bq + wave * 512]);
      stage16((const bf16*)(gK + ob), &sK[bk + wave * 512]);
      stage16((const bf16*)(gK + 64 * 8192 + ob), &sK[bk + (wave + 4) * 512]);
      stage16((const bf16*)(gK + 128 * 8192 + ob), &sK[bk + (wave + 8) * 512]);
      asm volatile("s_waitcnt vmcnt(4)" ::: "memory");
    } else {
      asm volatile("s_waitcnt vmcnt(0)" ::: "memory");
    }
    asm volatile("s_barrier" ::: "memory");
    __builtin_amdgcn_sched_barrier(0);
    bf16x8 aF = *(const bf16x8*)(&sQ[p * 2048 + (wave * 16 + (lane & 15)) * 32 + rx]);
    __builtin_amdgcn_s_setprio(1);
    #pragma unroll
    for (int j = 0; j < 11; ++j) {
      bf16x8 bF = *(const bf16x8*)(&sK[p * 6144 + (j * 16 + (lane & 15)) * 32 + rx]);
      sacc[j] = __builtin_amdgcn_mfma_f32_16x16x32_bf16(aF, bF, sacc[j], 0, 0, 0);
    }
    __builtin_amdgcn_s_setprio(0);
    asm volatile("s_waitcnt lgkmcnt(0)" ::: "memory");
    __builtin_amdgcn_sched_barrier(0);
    asm volatile("s_barrier" ::: "memory");
  }

  int rbase = wave * 16 + ((lane >> 4) << 2);
  #pragma unroll
  for (int rr = 0; rr < 4; ++rr) {
    int srow = mt * 64 + rbase + rr;
    float mx = -1e30f;
    #pragma unroll
    for (int j = 0; j < 11; ++j) {
      int col = j * 16 + (lane & 15);
      float v = sacc[j][rr] * 0.04419417382415922f;
      v = (col <= srow) ? v : -1e9f;
      sacc[j][rr] = v;
      mx = fmaxf(mx, v);
    }
    #pragma unroll
    for (int off = 1; off < 16; off <<= 1) mx = fmaxf(mx, __shfl_xor(mx, off, 16));
    float sum = 0.f;
    #pragma unroll
    for (int j = 0; j < 11; ++j) {
      float e = __expf(sacc[j][rr] - mx);
      sacc[j][rr] = e;
      sum += e;
    }
    #pragma unroll
    for (int off = 1; off < 16; off <<= 1) sum += __shfl_xor(sum, off, 16);
    float inv = 1.f / sum;
    #pragma unroll
    for (int j = 0; j < 11; ++j)
      sP[(rbase + rr) * 200 + j * 16 + (lane & 15)] = (bf16)(sacc[j][rr] * inv);
  }

  const char* gV = (const char*)Vb + (long)srw * 336 + scb;
  #pragma unroll 1
  for (int nc = 0; nc < 2; ++nc) {
    f32x4 oacc[16];
    #pragma unroll
    for (int t = 0; t < 16; ++t)
      #pragma unroll
      for (int rr = 0; rr < 4; ++rr) oacc[t][rr] = 0.f;

    for (int k0 = 0; k0 < 192; k0 += 32) {
      #pragma unroll
      for (int u = 0; u < 4; ++u)
        stage16((const bf16*)(gV + (long)(nc * 256 + u * 64) * 336 + (long)k0 * 2),
                &sV[(wave + u * 4) * 512]);
      __syncthreads();
      bf16x8 aF = *(const bf16x8*)(&sP[(wave * 16 + (lane & 15)) * 200 + k0 + (lane >> 4) * 8]);
      __builtin_amdgcn_s_setprio(1);
      #pragma unroll
      for (int t = 0; t < 16; ++t) {
        bf16x8 bF = *(const bf16x8*)(&sV[(t * 16 + (lane & 15)) * 32 + rx]);
        oacc[t] = __builtin_amdgcn_mfma_f32_16x16x32_bf16(aF, bF, oacc[t], 0, 0, 0);
      }
      __builtin_amdgcn_s_setprio(0);
      __syncthreads();
    }
    #pragma unroll
    for (int t = 0; t < 16; ++t) {
      int d = nc * 256 + t * 16 + (lane & 15);
      #pragma unroll
      for (int rr = 0; rr < 4; ++rr) {
        int srow = mt * 64 + rbase + rr;
        if (srow < 168)
          O[((long)bl * 168 + srow) * 4096 + h * 512 + d] = (bf16)oacc[t][rr];
      }
    }
  }
}

// ---------------------------------------------------------------------------
// Weight transpose + f32->bf16
// ---------------------------------------------------------------------------
__global__ __launch_bounds__(256) void transpose_w(const float* __restrict__ in,
                                                   bf16* __restrict__ out,
                                                   int K, int N, long ostride, long obase)
{
  long zi = (long)blockIdx.z * K * N;
  long zo = (long)blockIdx.z * ostride + obase;
  __shared__ float t[32][33];
  int tx = threadIdx.x & 31;
  int ty = threadIdx.x >> 5;
  int n0 = blockIdx.x * 32;
  int k0 = blockIdx.y * 32;
  #pragma unroll
  for (int r = 0; r < 4; ++r) {
    int k = k0 + ty + r * 8, n = n0 + tx;
    if (k < K && n < N) t[ty + r * 8][tx] = in[zi + (long)k * N + n];
  }
  __syncthreads();
  #pragma unroll
  for (int r = 0; r < 4; ++r) {
    int n = n0 + ty + r * 8, k = k0 + tx;
    if (n < N && k < K) out[zo + (long)n * K + k] = (bf16)t[tx][ty + r * 8];
  }
}

__global__ __launch_bounds__(256) void merge_bias(const float* __restrict__ q,
                                                  const float* __restrict__ k,
                                                  const float* __restrict__ v,
                                                  float* __restrict__ o)
{
  int idx = blockIdx.x * 256 + threadIdx.x;
  if (idx >= 4 * 12288) return;
  int l = idx / 12288, r = idx - l * 12288;
  int part = r >> 12, n = r & 4095;
  const float* s = (part == 0) ? q : (part == 1) ? k : v;
  o[idx] = s[l * 4096 + n];
}

// ---------------------------------------------------------------------------
// Input projection: h = (x @ in_w + in_b) * sqrt(512) + pos_encoding
// ---------------------------------------------------------------------------
__global__ __launch_bounds__(256) void input_proj(const float* __restrict__ x,
                                                  const float* __restrict__ w,
                                                  const float* __restrict__ b,
                                                  float* __restrict__ hf,
                                                  bf16* __restrict__ hb)
{
  long idx = (long)blockIdx.x * 256 + threadIdx.x;
  long row = idx >> 9;
  int d = (int)(idx & 511);
  float acc = b[d];
  const float* xr = x + row * 10;
  #pragma unroll
  for (int f = 0; f < 10; ++f) acc += xr[f] * w[f * 512 + d];
  int s = (int)(row % 168);
  float rate = __expf(-(float)(d & ~1) * (9.210340371976184f / 512.f));
  float ang = (float)s * rate;
  float pe = (d & 1) ? cosf(ang) : sinf(ang);
  float v = acc * 22.627416997969522f + pe;
  hf[idx] = v;
  hb[idx] = (bf16)v;
}

// ---------------------------------------------------------------------------
// LayerNorm over 512; Yf write optional (nullptr -> skip)
// ---------------------------------------------------------------------------
__device__ __forceinline__ float block_sum256(float v, float* red)
{
  #pragma unroll
  for (int o = 32; o > 0; o >>= 1) v += __shfl_xor(v, o, 64);
  if ((threadIdx.x & 63) == 0) red[threadIdx.x >> 6] = v;
  __syncthreads();
  float tot = red[0] + red[1] + red[2] + red[3];
  __syncthreads();
  return tot;
}

__global__ __launch_bounds__(256) void ln_kernel(const float* __restrict__ X,
                                                 const float* __restrict__ g,
                                                 const float* __restrict__ bta,
                                                 float* __restrict__ Yf,
                                                 bf16* __restrict__ Yb)
{
  __shared__ float red[4];
  long row = blockIdx.x;
  int t = threadIdx.x;
  const float* x = X + row * 512;
  float v0 = x[t], v1 = x[t + 256];
  float mean = block_sum256(v0 + v1, red) * (1.f / 512.f);
  float d0 = v0 - mean, d1 = v1 - mean;
  float var = block_sum256(d0 * d0 + d1 * d1, red) * (1.f / 512.f);
  float rs = rsqrtf(var + 1e-9f);
  float y0 = d0 * rs * g[t] + bta[t];
  float y1 = d1 * rs * g[t + 256] + bta[t + 256];
  if (Yf) {
    Yf[row * 512 + t] = y0;
    Yf[row * 512 + t + 256] = y1;
  }
  Yb[row * 512 + t] = (bf16)y0;
  Yb[row * 512 + t + 256] = (bf16)y1;
}

// ---------------------------------------------------------------------------
// Output projection
// ---------------------------------------------------------------------------
__global__ __launch_bounds__(256) void out_proj(const float* __restrict__ hf,
                                                const float* __restrict__ ow,
                                                const float* __restrict__ ob,
                                                float* __restrict__ out)
{
  int gid = blockIdx.x * 256 + threadIdx.x;
  int wid = gid >> 6;
  int lane = gid & 63;
  if (wid >= 64 * 48) return;
  int b = wid / 48, j = wid - b * 48;
  long row = (long)b * 168 + 120 + j;
  const float* x = hf + row * 512;
  float s = 0.f;
  #pragma unroll
  for (int t = 0; t < 8; ++t) s += x[lane + t * 64] * ow[lane + t * 64];
  #pragma unroll
  for (int o = 32; o > 0; o >>= 1) s += __shfl_xor(s, o, 64);
  if (lane == 0) out[wid] = s + ob[0];
}

// ---------------------------------------------------------------------------
extern "C" void kernel_launch(void* const* d_in, const int* in_sizes, int n_in,
                              void* d_out, int out_size, void* d_ws, size_t ws_size,
                              hipStream_t stream)
{
  const float* x     = (const float*)d_in[0];
  const float* in_w  = (const float*)d_in[2];
  const float* in_b  = (const float*)d_in[3];
  const float* wq_w  = (const float*)d_in[4];
  const float* wq_b  = (const float*)d_in[5];
  const float* wk_w  = (const float*)d_in[6];
  const float* wk_b  = (const float*)d_in[7];
  const float* wv_w  = (const float*)d_in[8];
  const float* wv_b  = (const float*)d_in[9];
  const float* dn_w  = (const float*)d_in[10];
  const float* dn_b  = (const float*)d_in[11];
  const float* mh_w  = (const float*)d_in[12];
  const float* mh_b  = (const float*)d_in[13];
  const float* mo_w  = (const float*)d_in[14];
  const float* mo_b  = (const float*)d_in[15];
  const float* ln1_g = (const float*)d_in[16];
  const float* ln1_b = (const float*)d_in[17];
  const float* ln3_g = (const float*)d_in[18];
  const float* ln3_b = (const float*)d_in[19];
  const float* out_w = (const float*)d_in[20];
  const float* out_b = (const float*)d_in[21];
  float* out = (float*)d_out;

  auto al = [](size_t b) { return (b + 255) & ~(size_t)255; };
  size_t off = 0;
  auto alloc = [&](size_t bytes) -> char* {
    char* p = (char*)d_ws + off;
    off += al(bytes);
    return p;
  };

  bf16*  wqkvT = (bf16*)alloc(4L * 12288 * 512 * 2);  // [L][12288][512]
  float* qkvB  = (float*)alloc(4L * 12288 * 4);
  bf16*  dnT   = (bf16*)alloc(4L * 512 * 4096 * 2);
  bf16*  mhT   = (bf16*)alloc(4L * 2048 * 512 * 2);
  bf16*  moT   = (bf16*)alloc(4L * 512 * 2048 * 2);
  float* hF    = (float*)alloc(10752L * 512 * 4);     // residual stream f32
  bf16*  hB    = (bf16*)alloc(10752L * 512 * 2);      // residual stream bf16
  float* Xf    = (float*)alloc(10752L * 512 * 4);     // pre-LN full-M scratch

  const int  CB = 16, NC = 4;
  const long Mc = (long)CB * 168;                     // 2688
  const long qstride = Mc * 4096;                     // elems
  bf16* Qc = (bf16*)alloc((size_t)(3 * qstride) * 2); // 66 MB
  bf16* Kc  = Qc + qstride;
  bf16* Vtc = Qc + 2 * qstride;
  bf16* h1b = Qc;                                     // [10752,512]  (alias)
  bf16* m1c = Qc + 10752L * 512;                      // [10752,2048] (alias)
  // dn split-K partials: 4 x [2688][512] f32 = 22.02 MB over the dead Kc
  // region (K only read by attn_fused, already done; next chunk's QKV
  // rewrites Kc afterwards — stream-ordered).
  float* dnP = (float*)Kc;
  const long pstride = Mc * 512;                      // partial stride (elems)

  transpose_w<<<dim3(128, 16, 4), 256, 0, stream>>>(wq_w, wqkvT, 512, 4096, 12288L * 512, 0);
  transpose_w<<<dim3(128, 16, 4), 256, 0, stream>>>(wk_w, wqkvT, 512, 4096, 12288L * 512, 4096L * 512);
  transpose_w<<<dim3(128, 16, 4), 256, 0, stream>>>(wv_w, wqkvT, 512, 4096, 12288L * 512, 8192L * 512);
  transpose_w<<<dim3(16, 128, 4), 256, 0, stream>>>(dn_w, dnT, 4096, 512, 512L * 4096, 0);
  transpose_w<<<dim3(64, 16, 4), 256, 0, stream>>>(mh_w, mhT, 512, 2048, 2048L * 512, 0);
  transpose_w<<<dim3(16, 64, 4), 256, 0, stream>>>(mo_w, moT, 2048, 512, 512L * 2048, 0);
  merge_bias<<<(4 * 12288 + 255) / 256, 256, 0, stream>>>(wq_b, wk_b, wv_b, qkvB);

  input_proj<<<10752 * 512 / 256, 256, 0, stream>>>(x, in_w, in_b, hF, hB);

  const int cM = (int)(Mc / 128);   // 21

  for (int l = 0; l < 4; ++l) {
    for (int c = 0; c < NC; ++c) {
      long row0 = (long)c * Mc;

      gemm2<<<dim3(cM, 96), 256, 0, stream>>>(
          hB + row0 * 512, wqkvT + (long)l * 12288 * 512, nullptr, Qc,
          qkvB + (long)l * 12288, nullptr, nullptr,
          12288, 512, 512, 512, 0, qstride, MODE_BIAS | MODE_QKV);

      attn_fused<<<dim3(3, CB * 8), 256, 0, stream>>>(Qc, Kc, Vtc, Qc);

      // dn split-K=4 -> 336 blocks of 32 steps, f32 partials in dead Kc
      gemm2<<<dim3(cM, 4, 4), 256, 0, stream>>>(
          Qc, dnT + (long)l * 512 * 4096, dnP, nullptr,
          nullptr, nullptr, nullptr,
          512, 1024, 4096, 4096, 512, pstride, MODE_PART);
      dn_reduce<<<(int)(Mc * 512 / 1024), 256, 0, stream>>>(
          Xf + row0 * 512, dnP, hF + row0 * 512, dn_b + (long)l * 512,
          Mc * 512, pstride);
    }

    ln_kernel<<<10752, 256, 0, stream>>>(Xf, ln1_g + l * 512, ln1_b + l * 512,
                                         nullptr, h1b);

    gemm2<<<dim3(84, 16), 256, 0, stream>>>(
        h1b, mhT + (long)l * 2048 * 512, nullptr, m1c,
        mh_b + (long)l * 2048, nullptr, nullptr,
        2048, 512, 512, 512, 2048, 0, MODE_BIAS | MODE_RELU | MODE_BF16);

    gemm2<<<dim3(84, 4), 256, 0, stream>>>(
        m1c, moT + (long)l * 512 * 2048, Xf, nullptr,
        mo_b + (long)l * 512, nullptr, h1b,
        512, 2048, 2048, 2048, 512, 0, MODE_BIAS | MODE_RESB | MODE_F32);

    ln_kernel<<<10752, 256, 0, stream>>>(Xf, ln3_g + l * 512, ln3_b + l * 512,
                                         hF, hB);
  }

  out_proj<<<(64 * 48 * 64) / 256, 256, 0, stream>>>(hF, out_w, out_b, out);
}

// Round 8
// 2712.238 us; speedup vs baseline: 1.0157x; 1.0157x over previous
//
#include <hip/hip_runtime.h>
#include <hip/hip_bf16.h>

typedef __bf16 bf16;
typedef __bf16 bf16x8 __attribute__((ext_vector_type(8)));
typedef __bf16 bf16x4v __attribute__((ext_vector_type(4)));
typedef float f32x4 __attribute__((ext_vector_type(4)));

#define MODE_BIAS 1
#define MODE_RELU 2
#define MODE_BF16 4
#define MODE_F32  8
#define MODE_RES  16    // f32 residual
#define MODE_RESB 32    // bf16 residual
#define MODE_QKV  128
#define MODE_PART 256   // split-K: write f32 partial at Cf + z*qstride

// ---------------------------------------------------------------------------
// Async 16B global->LDS stage
// ---------------------------------------------------------------------------
__device__ __forceinline__ void stage16(const bf16* g, bf16* l)
{
  __builtin_amdgcn_global_load_lds(
      (const __attribute__((address_space(1))) void*)g,
      (__attribute__((address_space(3))) void*)l, 16, 0, 0);
}

// ---------------------------------------------------------------------------
// gemm2: C[M,N] = A[M,K]*B^T (B is [N,K]).  M%128==0, N%128==0, K%32==0.
// 128x128 tile.  K-loop = HYBRID-DEPTH ring at BK=32 (r4/r6/r7 ledger:
// wait-distance and occupancy are the levers, barrier count is not —
// dist-2@3blk = dist-1@5blk = 68µs, dist-1@3blk = 77µs):
//   A (activations, XCD-L2-hot ~200-400cyc): 2 slabs, distance-1 (16 KB)
//   B (weights, L3/HBM ~500-900cyc):         3 slabs, distance-2 (24 KB)
// 40 KB total -> 4 blocks/CU WITH B at distance-2.
// Phase t: issue A(t+1)->sA[(t+1)&1], B(t+2)->sB[(t+2)%3]; counted wait
// vmcnt(6) (FIFO drains exactly A(t),B(t); tail 4 then 0); s_barrier;
// ds_read slab t; MFMA; lgkmcnt(0); s_barrier.  2-barrier ordering is
// r6's proven phase shape.  16B k-units XOR-swizzled via inverse-permuted
// GLOBAL source + permuted ds_read offset (conflict-free, r2/r4).
// r5 lesson: no cross-XCD atomics; MODE_PART writes per-z partial buffers.
// ---------------------------------------------------------------------------
__global__ __launch_bounds__(256) void gemm2(
    const bf16* __restrict__ A, const bf16* __restrict__ B,
    float* __restrict__ Cf, bf16* __restrict__ Cb,
    const float* __restrict__ bias, const float* __restrict__ resf,
    const bf16* __restrict__ resb,
    int N, int K, int lda, int ldb, int ldc, long qstride, int mode)
{
  __shared__ __attribute__((aligned(16))) bf16 smem[20480];  // 40 KB
  bf16* sA = smem;             // [2 slabs][128][32] = 16 KB
  bf16* sB = smem + 8192;      // [3 slabs][128][32] = 24 KB

  int tid  = threadIdx.x;
  int lane = tid & 63;
  int wave = tid >> 6;
  int wm = (wave >> 1) * 64;
  int wn = (wave & 1) * 64;

  // XCD-chunked bijective swizzle (m204 variant), per z-slice
  int nwg = gridDim.x * gridDim.y;
  int i0  = blockIdx.y * gridDim.x + blockIdx.x;
  int q   = nwg >> 3, r = nwg & 7;
  int xcd = i0 & 7, jj = i0 >> 3;
  int lid = (xcd < r ? xcd * (q + 1) : r * (q + 1) + (xcd - r) * q) + jj;
  int bx = lid % gridDim.x;
  int by = lid / gridDim.x;
  int bm0 = bx * 128;
  int bn0 = by * 128;
  long ks = (long)blockIdx.z * K;      // K-split column offset

  f32x4 acc[4][4];
  #pragma unroll
  for (int i = 0; i < 4; ++i)
    #pragma unroll
    for (int j = 0; j < 4; ++j)
      #pragma unroll
      for (int rr = 0; rr < 4; ++rr) acc[i][j][rr] = 0.f;

  int seg0 = wave, seg1 = wave + 4;
  int csw = ((lane & 3) ^ ((lane >> 3) & 3)) * 16;   // swizzled byte col
  int r0s = seg0 * 16 + (lane >> 2);
  int r1s = seg1 * 16 + (lane >> 2);
  int rx = ((lane >> 4) ^ ((lane >> 1) & 3)) * 8;    // swizzled read offset

  const char* gA0 = (const char*)A + ((long)(bm0 + r0s) * lda + ks) * 2 + csw;
  const char* gA1 = (const char*)A + ((long)(bm0 + r1s) * lda + ks) * 2 + csw;
  const char* gB0 = (const char*)B + ((long)(bn0 + r0s) * ldb + ks) * 2 + csw;
  const char* gB1 = (const char*)B + ((long)(bn0 + r1s) * ldb + ks) * 2 + csw;

  int nt = K >> 5;                         // BK=32 steps (nt >= 3 in all uses)

  // prologue: A0, B0, B1 (issue order matters for the FIFO vmcnt counts)
  stage16((const bf16*)gA0, sA + seg0 * 512);
  stage16((const bf16*)gA1, sA + seg1 * 512);
  stage16((const bf16*)gB0, sB + seg0 * 512);
  stage16((const bf16*)gB1, sB + seg1 * 512);
  stage16((const bf16*)(gB0 + 64), sB + 4096 + seg0 * 512);
  stage16((const bf16*)(gB1 + 64), sB + 4096 + seg1 * 512);

  int bslot = 0, bstage = 2;
  for (int t = 0; t < nt; ++t) {
    int pa = t & 1;
    if (t + 1 < nt) {
      long ob = (long)(t + 1) * 64;
      int so = (pa ^ 1) * 4096;
      stage16((const bf16*)(gA0 + ob), sA + so + seg0 * 512);
      stage16((const bf16*)(gA1 + ob), sA + so + seg1 * 512);
    }
    if (t + 2 < nt) {
      long ob2 = (long)(t + 2) * 64;
      int sb = bstage * 4096;
      stage16((const bf16*)(gB0 + ob2), sB + sb + seg0 * 512);
      stage16((const bf16*)(gB1 + ob2), sB + sb + seg1 * 512);
      asm volatile("s_waitcnt vmcnt(6)" ::: "memory");   // A(t),B(t) landed
    } else if (t + 1 < nt) {
      asm volatile("s_waitcnt vmcnt(4)" ::: "memory");
    } else {
      asm volatile("s_waitcnt vmcnt(0)" ::: "memory");
    }
    asm volatile("s_barrier" ::: "memory");              // all waves' slab t in
    __builtin_amdgcn_sched_barrier(0);
    int poA = pa * 4096, poB = bslot * 4096;
    bf16x8 aF[4], bF[4];
    #pragma unroll
    for (int i = 0; i < 4; ++i)
      aF[i] = *(const bf16x8*)(&sA[poA + (wm + i * 16 + (lane & 15)) * 32 + rx]);
    #pragma unroll
    for (int j = 0; j < 4; ++j)
      bF[j] = *(const bf16x8*)(&sB[poB + (wn + j * 16 + (lane & 15)) * 32 + rx]);
    __builtin_amdgcn_s_setprio(1);
    #pragma unroll
    for (int i = 0; i < 4; ++i)
      #pragma unroll
      for (int j = 0; j < 4; ++j)
        acc[i][j] = __builtin_amdgcn_mfma_f32_16x16x32_bf16(aF[i], bF[j], acc[i][j], 0, 0, 0);
    __builtin_amdgcn_s_setprio(0);
    asm volatile("s_waitcnt lgkmcnt(0)" ::: "memory");   // my slab-t reads done
    __builtin_amdgcn_sched_barrier(0);
    asm volatile("s_barrier" ::: "memory");              // safe to overwrite
    bslot = (bslot == 2) ? 0 : bslot + 1;
    bstage = (bstage == 2) ? 0 : bstage + 1;
  }

  int lg = lane >> 4;
  int r0 = lg * 4;
  int cc = lane & 15;

  if (mode & MODE_PART) {
    // ---- split-K: streamed f32 partial store (own buffer per z-slice) ----
    float* Cfz = Cf + (long)blockIdx.z * qstride;
    #pragma unroll
    for (int j = 0; j < 4; ++j) {
      int gn = bn0 + wn + j * 16 + cc;
      #pragma unroll
      for (int i = 0; i < 4; ++i)
        #pragma unroll
        for (int rr = 0; rr < 4; ++rr) {
          int gm = bm0 + wm + i * 16 + r0 + rr;
          Cfz[(long)gm * ldc + gn] = acc[i][j][rr];
        }
    }
    return;
  }

  if ((mode & MODE_QKV) && bn0 >= 8192) {
    // ---- V: transposed coalesced store via LDS (smem reused; K-loop done) ----
    bf16* sS = smem;   // [64][130] = 16.6 KB
    int nn0 = bn0 - 8192;
    #pragma unroll
    for (int ph = 0; ph < 2; ++ph) {
      if ((wn >> 6) == ph) {
        #pragma unroll
        for (int j = 0; j < 4; ++j) {
          int nl = j * 16 + cc;
          float bv = bias[bn0 + wn + j * 16 + cc];
          #pragma unroll
          for (int i = 0; i < 4; ++i)
            #pragma unroll
            for (int rr = 0; rr < 4; ++rr) {
              int m = wm + i * 16 + r0 + rr;
              sS[nl * 130 + m] = (bf16)(acc[i][j][rr] + bv);
            }
        }
      }
      __syncthreads();
      #pragma unroll
      for (int u = 0; u < 16; ++u) {
        int nrow = u * 4 + wave;
        int d = nn0 + ph * 64 + nrow;
        int hh = d >> 9, dd = d & 511;
        unsigned int pv = *(const unsigned int*)&sS[nrow * 130 + lane * 2];
        int m0 = bm0 + 2 * lane;
        int bl = m0 / 168;
        int s  = m0 - bl * 168;
        *(unsigned int*)&Cb[2 * qstride + ((long)(bl * 8 + hh) * 512 + dd) * 168 + s] = pv;
      }
      __syncthreads();
    }
    return;
  }

  if (mode & (MODE_QKV | MODE_BF16)) {
    // ---- bf16 coalesced store, two 64-row phases ([64][136] = 17.4 KB) ----
    bf16* sS = smem;
    long base;
    int ldx;
    if (mode & MODE_QKV) {
      int part = bn0 >> 12;           // 0=Q 1=K; tile never straddles parts
      base = (long)part * qstride + (bn0 & 4095);
      ldx = 4096;
    } else {
      base = (long)bn0;
      ldx = ldc;
    }
    #pragma unroll
    for (int ph = 0; ph < 2; ++ph) {
      if ((wm >> 6) == ph) {
        #pragma unroll
        for (int j = 0; j < 4; ++j) {
          float bv = (mode & MODE_BIAS) ? bias[bn0 + wn + j * 16 + cc] : 0.f;
          #pragma unroll
          for (int i = 0; i < 4; ++i) {
            #pragma unroll
            for (int rr = 0; rr < 4; ++rr) {
              float v = acc[i][j][rr] + bv;
              if (mode & MODE_RELU) v = fmaxf(v, 0.f);
              sS[(i * 16 + r0 + rr) * 136 + wn + j * 16 + cc] = (bf16)v;
            }
          }
        }
      }
      __syncthreads();
      #pragma unroll
      for (int it = 0; it < 4; ++it) {
        int idx = it * 256 + tid;
        int row = idx >> 4, seg = idx & 15;
        bf16x8 v = *(const bf16x8*)&sS[row * 136 + seg * 8];
        *(bf16x8*)&Cb[base + (long)(bm0 + ph * 64 + row) * ldx + seg * 8] = v;
      }
      __syncthreads();
    }
    return;
  }

  // ---- generic f32/bf16 epilogue (mo uses RESB path) ----
  #pragma unroll
  for (int j = 0; j < 4; ++j) {
    int gn = bn0 + wn + j * 16 + cc;
    float bv = (mode & MODE_BIAS) ? bias[gn] : 0.f;
    #pragma unroll
    for (int i = 0; i < 4; ++i) {
      #pragma unroll
      for (int rr = 0; rr < 4; ++rr) {
        int gm = bm0 + wm + i * 16 + r0 + rr;
        float v = acc[i][j][rr] + bv;
        if (mode & MODE_RES)  v += resf[(long)gm * ldc + gn];
        if (mode & MODE_RESB) v += (float)resb[(long)gm * ldc + gn];
        if (mode & MODE_RELU) v = fmaxf(v, 0.f);
        if (mode & MODE_F32) {
          Cf[(long)gm * ldc + gn] = v;
        } else {
          Cb[(long)gm * ldc + gn] = (bf16)v;
        }
      }
    }
  }
}

// ---------------------------------------------------------------------------
// dn_reduce: Xf[i] = P0[i]+P1[i]+P2[i]+P3[i] + hF[i] + bias[i&511]
// ---------------------------------------------------------------------------
__global__ __launch_bounds__(256) void dn_reduce(
    float* __restrict__ Xf, const float* __restrict__ P,
    const float* __restrict__ hF, const float* __restrict__ bias,
    long n, long pstride)
{
  long i = ((long)blockIdx.x * 256 + threadIdx.x) * 4;
  if (i >= n) return;
  int d = (int)(i & 511);
  float4 v  = *(const float4*)&hF[i];
  float4 bv = *(const float4*)&bias[d];
  v.x += bv.x; v.y += bv.y; v.z += bv.z; v.w += bv.w;
  #pragma unroll
  for (int z = 0; z < 4; ++z) {
    float4 p = *(const float4*)&P[(long)z * pstride + i];
    v.x += p.x; v.y += p.y; v.z += p.z; v.w += p.w;
  }
  *(float4*)&Xf[i] = v;
}

// ---------------------------------------------------------------------------
// FUSED ATTENTION (r2-proven): per (m-tile of 64 q-rows, bh) block.
// QK^T loop: 2-slab double buffer with COUNTED vmcnt(4) + raw barriers.
// ---------------------------------------------------------------------------
__global__ __launch_bounds__(256) void attn_fused(
    const bf16* __restrict__ Q, const bf16* __restrict__ K,
    const bf16* __restrict__ Vt, bf16* __restrict__ O)
{
  __shared__ __attribute__((aligned(16))) bf16 sQ[2 * 64 * 32];
  __shared__ __attribute__((aligned(16))) bf16 sK[2 * 192 * 32];
  __shared__ __attribute__((aligned(16))) bf16 sP[64 * 200];
  __shared__ __attribute__((aligned(16))) bf16 sV[256 * 32];

  int mt = blockIdx.x;
  int bh = blockIdx.y;
  int bl = bh >> 3, h = bh & 7;
  int tid = threadIdx.x, lane = tid & 63, wave = tid >> 6;

  const bf16* Qb = Q + ((long)bl * 168 + mt * 64) * 4096 + h * 512;
  const bf16* Kb = K + (long)bl * 168 * 4096 + h * 512;
  const bf16* Vb = Vt + (long)bh * 512 * 168;

  #pragma unroll
  for (int idx = tid; idx < 64 * 16; idx += 256) {
    int rr = idx >> 4;
    sP[rr * 200 + 176 + (idx & 15)] = (bf16)0.f;
  }

  int srw = wave * 16 + (lane >> 2);
  int scb = ((lane & 3) ^ ((lane >> 3) & 3)) * 16;
  int rx  = ((lane >> 4) ^ ((lane >> 1) & 3)) * 8;

  const char* gQ = (const char*)Qb + (long)srw * 8192 + scb;
  const char* gK = (const char*)Kb + (long)srw * 8192 + scb;

  f32x4 sacc[11];
  #pragma unroll
  for (int j = 0; j < 11; ++j)
    #pragma unroll
    for (int rr = 0; rr < 4; ++rr) sacc[j][rr] = 0.f;

  stage16((const bf16*)gQ, &sQ[wave * 512]);
  stage16((const bf16*)gK, &sK[wave * 512]);
  stage16((const bf16*)(gK + 64 * 8192), &sK[(wave + 4) * 512]);
  stage16((const bf16*)(gK + 128 * 8192), &sK[(wave + 8) * 512]);

  for (int t = 0; t < 16; ++t) {
    int p = t & 1;
    if (t < 15) {
      long ob = (long)(t + 1) * 64;
      int bq = (p ^ 1) * 2048, bk = (p ^ 1) * 6144;
      stage16((const bf16*)(gQ + ob), &sQ[bq + wave * 512]);
      stage16((const bf16*)(gK + ob), &sK[bk + wave * 512]);
      stage16((const bf16*)(gK + 64 * 8192 + ob), &sK[bk + (wave + 4) * 512]);
      stage16((const bf16*)(gK + 128 * 8192 + ob), &sK[bk + (wave + 8) * 512]);
      asm volatile("s_waitcnt vmcnt(4)" ::: "memory");
    } else {
      asm volatile("s_waitcnt vmcnt(0)" ::: "memory");
    }
    asm volatile("s_barrier" ::: "memory");
    __builtin_amdgcn_sched_barrier(0);
    bf16x8 aF = *(const bf16x8*)(&sQ[p * 2048 + (wave * 16 + (lane & 15)) * 32 + rx]);
    __builtin_amdgcn_s_setprio(1);
    #pragma unroll
    for (int j = 0; j < 11; ++j) {
      bf16x8 bF = *(const bf16x8*)(&sK[p * 6144 + (j * 16 + (lane & 15)) * 32 + rx]);
      sacc[j] = __builtin_amdgcn_mfma_f32_16x16x32_bf16(aF, bF, sacc[j], 0, 0, 0);
    }
    __builtin_amdgcn_s_setprio(0);
    asm volatile("s_waitcnt lgkmcnt(0)" ::: "memory");
    __builtin_amdgcn_sched_barrier(0);
    asm volatile("s_barrier" ::: "memory");
  }

  int rbase = wave * 16 + ((lane >> 4) << 2);
  #pragma unroll
  for (int rr = 0; rr < 4; ++rr) {
    int srow = mt * 64 + rbase + rr;
    float mx = -1e30f;
    #pragma unroll
    for (int j = 0; j < 11; ++j) {
      int col = j * 16 + (lane & 15);
      float v = sacc[j][rr] * 0.04419417382415922f;
      v = (col <= srow) ? v : -1e9f;
      sacc[j][rr] = v;
      mx = fmaxf(mx, v);
    }
    #pragma unroll
    for (int off = 1; off < 16; off <<= 1) mx = fmaxf(mx, __shfl_xor(mx, off, 16));
    float sum = 0.f;
    #pragma unroll
    for (int j = 0; j < 11; ++j) {
      float e = __expf(sacc[j][rr] - mx);
      sacc[j][rr] = e;
      sum += e;
    }
    #pragma unroll
    for (int off = 1; off < 16; off <<= 1) sum += __shfl_xor(sum, off, 16);
    float inv = 1.f / sum;
    #pragma unroll
    for (int j = 0; j < 11; ++j)
      sP[(rbase + rr) * 200 + j * 16 + (lane & 15)] = (bf16)(sacc[j][rr] * inv);
  }

  const char* gV = (const char*)Vb + (long)srw * 336 + scb;
  #pragma unroll 1
  for (int nc = 0; nc < 2; ++nc) {
    f32x4 oacc[16];
    #pragma unroll
    for (int t = 0; t < 16; ++t)
      #pragma unroll
      for (int rr = 0; rr < 4; ++rr) oacc[t][rr] = 0.f;

    for (int k0 = 0; k0 < 192; k0 += 32) {
      #pragma unroll
      for (int u = 0; u < 4; ++u)
        stage16((const bf16*)(gV + (long)(nc * 256 + u * 64) * 336 + (long)k0 * 2),
                &sV[(wave + u * 4) * 512]);
      __syncthreads();
      bf16x8 aF = *(const bf16x8*)(&sP[(wave * 16 + (lane & 15)) * 200 + k0 + (lane >> 4) * 8]);
      __builtin_amdgcn_s_setprio(1);
      #pragma unroll
      for (int t = 0; t < 16; ++t) {
        bf16x8 bF = *(const bf16x8*)(&sV[(t * 16 + (lane & 15)) * 32 + rx]);
        oacc[t] = __builtin_amdgcn_mfma_f32_16x16x32_bf16(aF, bF, oacc[t], 0, 0, 0);
      }
      __builtin_amdgcn_s_setprio(0);
      __syncthreads();
    }
    #pragma unroll
    for (int t = 0; t < 16; ++t) {
      int d = nc * 256 + t * 16 + (lane & 15);
      #pragma unroll
      for (int rr = 0; rr < 4; ++rr) {
        int srow = mt * 64 + rbase + rr;
        if (srow < 168)
          O[((long)bl * 168 + srow) * 4096 + h * 512 + d] = (bf16)oacc[t][rr];
      }
    }
  }
}

// ---------------------------------------------------------------------------
// Weight transpose + f32->bf16
// ---------------------------------------------------------------------------
__global__ __launch_bounds__(256) void transpose_w(const float* __restrict__ in,
                                                   bf16* __restrict__ out,
                                                   int K, int N, long ostride, long obase)
{
  long zi = (long)blockIdx.z * K * N;
  long zo = (long)blockIdx.z * ostride + obase;
  __shared__ float t[32][33];
  int tx = threadIdx.x & 31;
  int ty = threadIdx.x >> 5;
  int n0 = blockIdx.x * 32;
  int k0 = blockIdx.y * 32;
  #pragma unroll
  for (int r = 0; r < 4; ++r) {
    int k = k0 + ty + r * 8, n = n0 + tx;
    if (k < K && n < N) t[ty + r * 8][tx] = in[zi + (long)k * N + n];
  }
  __syncthreads();
  #pragma unroll
  for (int r = 0; r < 4; ++r) {
    int n = n0 + ty + r * 8, k = k0 + tx;
    if (n < N && k < K) out[zo + (long)n * K + k] = (bf16)t[tx][ty + r * 8];
  }
}

__global__ __launch_bounds__(256) void merge_bias(const float* __restrict__ q,
                                                  const float* __restrict__ k,
                                                  const float* __restrict__ v,
                                                  float* __restrict__ o)
{
  int idx = blockIdx.x * 256 + threadIdx.x;
  if (idx >= 4 * 12288) return;
  int l = idx / 12288, r = idx - l * 12288;
  int part = r >> 12, n = r & 4095;
  const float* s = (part == 0) ? q : (part == 1) ? k : v;
  o[idx] = s[l * 4096 + n];
}

// ---------------------------------------------------------------------------
// Input projection: h = (x @ in_w + in_b) * sqrt(512) + pos_encoding
// ---------------------------------------------------------------------------
__global__ __launch_bounds__(256) void input_proj(const float* __restrict__ x,
                                                  const float* __restrict__ w,
                                                  const float* __restrict__ b,
                                                  float* __restrict__ hf,
                                                  bf16* __restrict__ hb)
{
  long idx = (long)blockIdx.x * 256 + threadIdx.x;
  long row = idx >> 9;
  int d = (int)(idx & 511);
  float acc = b[d];
  const float* xr = x + row * 10;
  #pragma unroll
  for (int f = 0; f < 10; ++f) acc += xr[f] * w[f * 512 + d];
  int s = (int)(row % 168);
  float rate = __expf(-(float)(d & ~1) * (9.210340371976184f / 512.f));
  float ang = (float)s * rate;
  float pe = (d & 1) ? cosf(ang) : sinf(ang);
  float v = acc * 22.627416997969522f + pe;
  hf[idx] = v;
  hb[idx] = (bf16)v;
}

// ---------------------------------------------------------------------------
// LayerNorm over 512; Yf write optional (nullptr -> skip)
// ---------------------------------------------------------------------------
__device__ __forceinline__ float block_sum256(float v, float* red)
{
  #pragma unroll
  for (int o = 32; o > 0; o >>= 1) v += __shfl_xor(v, o, 64);
  if ((threadIdx.x & 63) == 0) red[threadIdx.x >> 6] = v;
  __syncthreads();
  float tot = red[0] + red[1] + red[2] + red[3];
  __syncthreads();
  return tot;
}

__global__ __launch_bounds__(256) void ln_kernel(const float* __restrict__ X,
                                                 const float* __restrict__ g,
                                                 const float* __restrict__ bta,
                                                 float* __restrict__ Yf,
                                                 bf16* __restrict__ Yb)
{
  __shared__ float red[4];
  long row = blockIdx.x;
  int t = threadIdx.x;
  const float* x = X + row * 512;
  float v0 = x[t], v1 = x[t + 256];
  float mean = block_sum256(v0 + v1, red) * (1.f / 512.f);
  float d0 = v0 - mean, d1 = v1 - mean;
  float var = block_sum256(d0 * d0 + d1 * d1, red) * (1.f / 512.f);
  float rs = rsqrtf(var + 1e-9f);
  float y0 = d0 * rs * g[t] + bta[t];
  float y1 = d1 * rs * g[t + 256] + bta[t + 256];
  if (Yf) {
    Yf[row * 512 + t] = y0;
    Yf[row * 512 + t + 256] = y1;
  }
  Yb[row * 512 + t] = (bf16)y0;
  Yb[row * 512 + t + 256] = (bf16)y1;
}

// ---------------------------------------------------------------------------
// Output projection
// ---------------------------------------------------------------------------
__global__ __launch_bounds__(256) void out_proj(const float* __restrict__ hf,
                                                const float* __restrict__ ow,
                                                const float* __restrict__ ob,
                                                float* __restrict__ out)
{
  int gid = blockIdx.x * 256 + threadIdx.x;
  int wid = gid >> 6;
  int lane = gid & 63;
  if (wid >= 64 * 48) return;
  int b = wid / 48, j = wid - b * 48;
  long row = (long)b * 168 + 120 + j;
  const float* x = hf + row * 512;
  float s = 0.f;
  #pragma unroll
  for (int t = 0; t < 8; ++t) s += x[lane + t * 64] * ow[lane + t * 64];
  #pragma unroll
  for (int o = 32; o > 0; o >>= 1) s += __shfl_xor(s, o, 64);
  if (lane == 0) out[wid] = s + ob[0];
}

// ---------------------------------------------------------------------------
extern "C" void kernel_launch(void* const* d_in, const int* in_sizes, int n_in,
                              void* d_out, int out_size, void* d_ws, size_t ws_size,
                              hipStream_t stream)
{
  const float* x     = (const float*)d_in[0];
  const float* in_w  = (const float*)d_in[2];
  const float* in_b  = (const float*)d_in[3];
  const float* wq_w  = (const float*)d_in[4];
  const float* wq_b  = (const float*)d_in[5];
  const float* wk_w  = (const float*)d_in[6];
  const float* wk_b  = (const float*)d_in[7];
  const float* wv_w  = (const float*)d_in[8];
  const float* wv_b  = (const float*)d_in[9];
  const float* dn_w  = (const float*)d_in[10];
  const float* dn_b  = (const float*)d_in[11];
  const float* mh_w  = (const float*)d_in[12];
  const float* mh_b  = (const float*)d_in[13];
  const float* mo_w  = (const float*)d_in[14];
  const float* mo_b  = (const float*)d_in[15];
  const float* ln1_g = (const float*)d_in[16];
  const float* ln1_b = (const float*)d_in[17];
  const float* ln3_g = (const float*)d_in[18];
  const float* ln3_b = (const float*)d_in[19];
  const float* out_w = (const float*)d_in[20];
  const float* out_b = (const float*)d_in[21];
  float* out = (float*)d_out;

  auto al = [](size_t b) { return (b + 255) & ~(size_t)255; };
  size_t off = 0;
  auto alloc = [&](size_t bytes) -> char* {
    char* p = (char*)d_ws + off;
    off += al(bytes);
    return p;
  };

  bf16*  wqkvT = (bf16*)alloc(4L * 12288 * 512 * 2);  // [L][12288][512]
  float* qkvB  = (float*)alloc(4L * 12288 * 4);
  bf16*  dnT   = (bf16*)alloc(4L * 512 * 4096 * 2);
  bf16*  mhT   = (bf16*)alloc(4L * 2048 * 512 * 2);
  bf16*  moT   = (bf16*)alloc(4L * 512 * 2048 * 2);
  float* hF    = (float*)alloc(10752L * 512 * 4);     // residual stream f32
  bf16*  hB    = (bf16*)alloc(10752L * 512 * 2);      // residual stream bf16
  float* Xf    = (float*)alloc(10752L * 512 * 4);     // pre-LN full-M scratch

  const int  CB = 16, NC = 4;
  const long Mc = (long)CB * 168;                     // 2688
  const long qstride = Mc * 4096;                     // elems
  bf16* Qc = (bf16*)alloc((size_t)(3 * qstride) * 2); // 66 MB
  bf16* Kc  = Qc + qstride;
  bf16* Vtc = Qc + 2 * qstride;
  bf16* h1b = Qc;                                     // [10752,512]  (alias)
  bf16* m1c = Qc + 10752L * 512;                      // [10752,2048] (alias)
  // dn split-K partials: 4 x [2688][512] f32 = 22.02 MB over the dead Kc
  // region (K only read by attn_fused, already done; next chunk's QKV
  // rewrites Kc afterwards — stream-ordered).
  float* dnP = (float*)Kc;
  const long pstride = Mc * 512;                      // partial stride (elems)

  transpose_w<<<dim3(128, 16, 4), 256, 0, stream>>>(wq_w, wqkvT, 512, 4096, 12288L * 512, 0);
  transpose_w<<<dim3(128, 16, 4), 256, 0, stream>>>(wk_w, wqkvT, 512, 4096, 12288L * 512, 4096L * 512);
  transpose_w<<<dim3(128, 16, 4), 256, 0, stream>>>(wv_w, wqkvT, 512, 4096, 12288L * 512, 8192L * 512);
  transpose_w<<<dim3(16, 128, 4), 256, 0, stream>>>(dn_w, dnT, 4096, 512, 512L * 4096, 0);
  transpose_w<<<dim3(64, 16, 4), 256, 0, stream>>>(mh_w, mhT, 512, 2048, 2048L * 512, 0);
  transpose_w<<<dim3(16, 64, 4), 256, 0, stream>>>(mo_w, moT, 2048, 512, 512L * 2048, 0);
  merge_bias<<<(4 * 12288 + 255) / 256, 256, 0, stream>>>(wq_b, wk_b, wv_b, qkvB);

  input_proj<<<10752 * 512 / 256, 256, 0, stream>>>(x, in_w, in_b, hF, hB);

  const int cM = (int)(Mc / 128);   // 21

  for (int l = 0; l < 4; ++l) {
    for (int c = 0; c < NC; ++c) {
      long row0 = (long)c * Mc;

      gemm2<<<dim3(cM, 96), 256, 0, stream>>>(
          hB + row0 * 512, wqkvT + (long)l * 12288 * 512, nullptr, Qc,
          qkvB + (long)l * 12288, nullptr, nullptr,
          12288, 512, 512, 512, 0, qstride, MODE_BIAS | MODE_QKV);

      attn_fused<<<dim3(3, CB * 8), 256, 0, stream>>>(Qc, Kc, Vtc, Qc);

      // dn split-K=4 -> 336 blocks of 32 steps, f32 partials in dead Kc
      gemm2<<<dim3(cM, 4, 4), 256, 0, stream>>>(
          Qc, dnT + (long)l * 512 * 4096, dnP, nullptr,
          nullptr, nullptr, nullptr,
          512, 1024, 4096, 4096, 512, pstride, MODE_PART);
      dn_reduce<<<(int)(Mc * 512 / 1024), 256, 0, stream>>>(
          Xf + row0 * 512, dnP, hF + row0 * 512, dn_b + (long)l * 512,
          Mc * 512, pstride);
    }

    ln_kernel<<<10752, 256, 0, stream>>>(Xf, ln1_g + l * 512, ln1_b + l * 512,
                                         nullptr, h1b);

    gemm2<<<dim3(84, 16), 256, 0, stream>>>(
        h1b, mhT + (long)l * 2048 * 512, nullptr, m1c,
        mh_b + (long)l * 2048, nullptr, nullptr,
        2048, 512, 512, 512, 2048, 0, MODE_BIAS | MODE_RELU | MODE_BF16);

    gemm2<<<dim3(84, 4), 256, 0, stream>>>(
        m1c, moT + (long)l * 512 * 2048, Xf, nullptr,
        mo_b + (long)l * 512, nullptr, h1b,
        512, 2048, 2048, 2048, 512, 0, MODE_BIAS | MODE_RESB | MODE_F32);

    ln_kernel<<<10752, 256, 0, stream>>>(Xf, ln3_g + l * 512, ln3_b + l * 512,
                                         hF, hB);
  }

  out_proj<<<(64 * 48 * 64) / 256, 256, 0, stream>>>(hF, out_w, out_b, out);
}